// Round 1
// baseline (918.054 us; speedup 1.0000x reference)
//
#include <hip/hip_runtime.h>
#include <hip/hip_bf16.h>

#define D 768
#define NQ 64
#define NT 128          // corpus rows per block
#define KC 64           // k-chunk
#define NCH (D / KC)    // 12
#define TPB 256
#define SIMSTRIDE 133   // 64x133 fp32 sim tile (133 = 128+5, coprime-ish bank spread)

typedef float  f32x4  __attribute__((ext_vector_type(4)));
typedef _Float16 h16x8 __attribute__((ext_vector_type(8)));
typedef _Float16 h16x4 __attribute__((ext_vector_type(4)));

// ---------- top-k helpers (all static-indexed: stays in VGPRs) ----------
__device__ __forceinline__ bool kbetter(float v1, int i1, float v2, int i2) {
    return (v1 > v2) || (v1 == v2 && i1 < i2);
}

__device__ __forceinline__ void topk_insert(float (&tv)[16], int (&ti)[16], float v, int idx) {
    if (!kbetter(v, idx, tv[15], ti[15])) return;
    tv[15] = v; ti[15] = idx;
    #pragma unroll
    for (int s = 15; s >= 1; --s) {
        bool sw = kbetter(tv[s], ti[s], tv[s-1], ti[s-1]);
        float av = sw ? tv[s] : tv[s-1];
        float bv = sw ? tv[s-1] : tv[s];
        int   ai = sw ? ti[s] : ti[s-1];
        int   bi = sw ? ti[s-1] : ti[s];
        tv[s-1] = av; tv[s] = bv; ti[s-1] = ai; ti[s] = bi;
    }
}

__device__ __forceinline__ void bitonic16(float (&v)[16], int (&ix)[16]) {
    #pragma unroll
    for (int d = 8; d >= 1; d >>= 1) {
        #pragma unroll
        for (int i = 0; i < 16; ++i) {
            if ((i & d) == 0) {
                int j = i | d;
                bool sw = kbetter(v[j], ix[j], v[i], ix[i]);
                float av = sw ? v[j] : v[i];
                float bv = sw ? v[i] : v[j];
                int   ai = sw ? ix[j] : ix[i];
                int   bi = sw ? ix[i] : ix[j];
                v[i] = av; v[j] = bv; ix[i] = ai; ix[j] = bi;
            }
        }
    }
}

// merge sorted-desc 16-lists across lane pairs (lane ^ mask); both lanes end
// with the top-16 of the union (bitonic max-merge), re-sorted descending.
__device__ __forceinline__ void lane_merge(float (&v)[16], int (&ix)[16], int mask) {
    float pv[16]; int pix[16];
    #pragma unroll
    for (int i = 0; i < 16; ++i) {
        pv[i]  = __shfl_xor(v[15 - i], mask);
        pix[i] = __shfl_xor(ix[15 - i], mask);
    }
    #pragma unroll
    for (int i = 0; i < 16; ++i) {
        if (kbetter(pv[i], pix[i], v[i], ix[i])) { v[i] = pv[i]; ix[i] = pix[i]; }
    }
    bitonic16(v, ix);
}

// ---------- kernel 0: normalize Q rows, store fp16 hi/lo split ----------
__global__ __launch_bounds__(256)
void prep_kernel(const float* __restrict__ query, _Float16* __restrict__ qhi,
                 _Float16* __restrict__ qlo) {
    int b = blockIdx.x, t = threadIdx.x;
    const float* row = query + b * D;
    float vals[3]; float s = 0.f;
    #pragma unroll
    for (int j = 0; j < 3; ++j) { vals[j] = row[t + 256 * j]; s += vals[j] * vals[j]; }
    #pragma unroll
    for (int m = 1; m < 64; m <<= 1) s += __shfl_xor(s, m);
    __shared__ float ws4[4];
    if ((t & 63) == 0) ws4[t >> 6] = s;
    __syncthreads();
    float qn = sqrtf(ws4[0] + ws4[1] + ws4[2] + ws4[3]);
    #pragma unroll
    for (int j = 0; j < 3; ++j) {
        float vn = vals[j] / qn;
        _Float16 h = (_Float16)vn;
        float r = vn - (float)h;
        _Float16 l2 = (_Float16)(r * 2048.0f);
        qhi[b * D + t + 256 * j] = h;
        qlo[b * D + t + 256 * j] = l2;
    }
}

// ---------- kernel 1: fused split-fp16 MFMA sims + per-block top-16 ----------
__global__ __launch_bounds__(TPB, 2)
void sim_topk_kernel(const float* __restrict__ corpus,
                     const _Float16* __restrict__ qhi,
                     const _Float16* __restrict__ qlo,
                     float2* __restrict__ cand,   // [NQ][NB][16]
                     int N, int NB) {
    __shared__ __align__(16) char smem[34560];
    // layout: tileHi [128][64]h @0 (16KB), tileLo @16384 (16KB)
    //         sim (overlay) 64*133 f32 @0 (34048B), cnsq[128] f32 @34048
    int t = threadIdx.x, w = t >> 6, l = t & 63;
    int b = blockIdx.x, n0 = b * NT;

    f32x4 accH[4][2], accX[4][2];
    #pragma unroll
    for (int qf = 0; qf < 4; ++qf)
        #pragma unroll
        for (int nfl = 0; nfl < 2; ++nfl) { accH[qf][nfl] = (f32x4)(0.f); accX[qf][nfl] = (f32x4)(0.f); }
    float psum[8];
    #pragma unroll
    for (int j = 0; j < 8; ++j) psum[j] = 0.f;

    for (int c = 0; c < NCH; ++c) {
        float4 v[8];
        #pragma unroll
        for (int j = 0; j < 8; ++j) {
            int idx = t + TPB * j;
            int row = idx >> 4, k4 = idx & 15;
            int grow = n0 + row;
            if (grow < N)
                v[j] = *(const float4*)(corpus + (size_t)grow * D + c * KC + k4 * 4);
            else
                v[j] = make_float4(0.f, 0.f, 0.f, 0.f);
        }
        __syncthreads();   // chunk c-1 readers done; tiles writable
        #pragma unroll
        for (int j = 0; j < 8; ++j) {
            int idx = t + TPB * j;
            int row = idx >> 4, k4 = idx & 15;
            float4 x = v[j];
            psum[j] += x.x * x.x + x.y * x.y + x.z * x.z + x.w * x.w;
            h16x4 h, lo;
            h.x = (_Float16)x.x; h.y = (_Float16)x.y; h.z = (_Float16)x.z; h.w = (_Float16)x.w;
            lo.x = (_Float16)((x.x - (float)h.x) * 2048.0f);
            lo.y = (_Float16)((x.y - (float)h.y) * 2048.0f);
            lo.z = (_Float16)((x.z - (float)h.z) * 2048.0f);
            lo.w = (_Float16)((x.w - (float)h.w) * 2048.0f);
            int gb  = (((k4 >> 1) << 4) ^ ((row & 7) << 4)) + ((k4 & 1) << 3);
            *(h16x4*)(smem + row * 128 + gb)         = h;
            *(h16x4*)(smem + 16384 + row * 128 + gb) = lo;
        }
        __syncthreads();   // tiles visible
        // Q fragments for this chunk (global, L1/L2-hot)
        h16x8 qh[2][4], ql[2][4];
        int qk = c * KC + ((l >> 4) << 3);
        #pragma unroll
        for (int kk = 0; kk < 2; ++kk)
            #pragma unroll
            for (int qf = 0; qf < 4; ++qf) {
                int qrow = qf * 16 + (l & 15);
                qh[kk][qf] = *(const h16x8*)(qhi + qrow * D + qk + kk * 32);
                ql[kk][qf] = *(const h16x8*)(qlo + qrow * D + qk + kk * 32);
            }
        #pragma unroll
        for (int kk = 0; kk < 2; ++kk) {
            #pragma unroll
            for (int nfl = 0; nfl < 2; ++nfl) {
                int row = w * 32 + nfl * 16 + (l & 15);
                int gbyte = (kk * 64 + ((l >> 4) << 4)) ^ ((row & 7) << 4);
                h16x8 ch = *(const h16x8*)(smem + row * 128 + gbyte);
                h16x8 cl = *(const h16x8*)(smem + 16384 + row * 128 + gbyte);
                #pragma unroll
                for (int qf = 0; qf < 4; ++qf) {
                    accH[qf][nfl] = __builtin_amdgcn_mfma_f32_16x16x32_f16(qh[kk][qf], ch, accH[qf][nfl], 0, 0, 0);
                    accX[qf][nfl] = __builtin_amdgcn_mfma_f32_16x16x32_f16(qh[kk][qf], cl, accX[qf][nfl], 0, 0, 0);
                    accX[qf][nfl] = __builtin_amdgcn_mfma_f32_16x16x32_f16(ql[kk][qf], ch, accX[qf][nfl], 0, 0, 0);
                }
            }
        }
    }

    // corpus row sum-of-squares: reduce across the 16 threads covering each row
    #pragma unroll
    for (int j = 0; j < 8; ++j) {
        float s = psum[j];
        s += __shfl_xor(s, 1); s += __shfl_xor(s, 2);
        s += __shfl_xor(s, 4); s += __shfl_xor(s, 8);
        int row = (t >> 4) + 16 * j;
        if ((l & 15) == 0) *(float*)(smem + 34048 + row * 4) = s;
    }
    __syncthreads();   // all MFMA + cnsq done; tiles dead -> sim overlay OK

    float* sim  = (float*)smem;
    float* cnsq = (float*)(smem + 34048);
    #pragma unroll
    for (int nfl = 0; nfl < 2; ++nfl) {
        int n = w * 32 + nfl * 16 + (l & 15);
        float cn = sqrtf(cnsq[n]);
        #pragma unroll
        for (int qf = 0; qf < 4; ++qf) {
            #pragma unroll
            for (int r = 0; r < 4; ++r) {
                int q = qf * 16 + ((l >> 4) << 2) + r;
                float dot = accH[qf][nfl][r] + accX[qf][nfl][r] * (1.0f / 2048.0f);
                sim[q * SIMSTRIDE + n] = dot / cn;
            }
        }
    }
    __syncthreads();

    // per-query top-16 over this block's 128 rows: 4 threads per query
    int q = t >> 2, cc = t & 3;
    float tv[16]; int ti[16];
    #pragma unroll
    for (int s = 0; s < 16; ++s) { tv[s] = -INFINITY; ti[s] = 0x7fffffff; }
    for (int i = 0; i < 32; ++i) {
        int n = cc * 32 + i;
        int g = n0 + n;
        if (g < N) topk_insert(tv, ti, sim[q * SIMSTRIDE + n], g);
    }
    lane_merge(tv, ti, 1);
    lane_merge(tv, ti, 2);
    if ((l & 3) == 0) {
        float2* dst = cand + ((size_t)q * NB + b) * 16;
        #pragma unroll
        for (int s = 0; s < 16; ++s) dst[s] = make_float2(tv[s], __int_as_float(ti[s]));
    }
}

// ---------- kernel 2: merge per-block candidates -> final top-16 ----------
__global__ __launch_bounds__(256)
void merge_kernel(const float2* __restrict__ cand, float* __restrict__ out, int NB) {
    __shared__ float2 stage[4 * 16];
    int qq = blockIdx.x, t = threadIdx.x, w = t >> 6, l = t & 63;
    const float2* src = cand + (size_t)qq * NB * 16;
    int total = NB * 16;
    float tv[16]; int ti[16];
    #pragma unroll
    for (int s = 0; s < 16; ++s) { tv[s] = -INFINITY; ti[s] = 0x7fffffff; }
    for (int e = t; e < total; e += 256) {
        float2 ce = src[e];
        topk_insert(tv, ti, ce.x, __float_as_int(ce.y));
    }
    lane_merge(tv, ti, 1);  lane_merge(tv, ti, 2);  lane_merge(tv, ti, 4);
    lane_merge(tv, ti, 8);  lane_merge(tv, ti, 16); lane_merge(tv, ti, 32);
    if (l == 0) {
        #pragma unroll
        for (int s = 0; s < 16; ++s) stage[w * 16 + s] = make_float2(tv[s], __int_as_float(ti[s]));
    }
    __syncthreads();
    if (t == 0) {
        float fv[16]; int fi[16];
        #pragma unroll
        for (int s = 0; s < 16; ++s) { fv[s] = -INFINITY; fi[s] = 0x7fffffff; }
        for (int e = 0; e < 64; ++e)
            topk_insert(fv, fi, stage[e].x, __float_as_int(stage[e].y));
        #pragma unroll
        for (int s = 0; s < 16; ++s) {
            out[qq * 16 + s]            = fv[s];          // values
            out[NQ * 16 + qq * 16 + s]  = (float)fi[s];   // indices as fp32
        }
    }
}

extern "C" void kernel_launch(void* const* d_in, const int* in_sizes, int n_in,
                              void* d_out, int out_size, void* d_ws, size_t ws_size,
                              hipStream_t stream) {
    const float* query  = (const float*)d_in[0];
    const float* corpus = (const float*)d_in[1];
    int N  = in_sizes[1] / D;            // 500000
    int NB = (N + NT - 1) / NT;          // 3907
    char* ws = (char*)d_ws;
    _Float16* qhi = (_Float16*)ws;                         // 98304 B
    _Float16* qlo = (_Float16*)(ws + 98304);               // 98304 B
    float2*  cand = (float2*)(ws + 196608);                // 64*NB*16*8 B (~32 MB)
    float*   out  = (float*)d_out;

    prep_kernel<<<NQ, 256, 0, stream>>>(query, qhi, qlo);
    sim_topk_kernel<<<NB, TPB, 0, stream>>>(corpus, qhi, qlo, cand, N, NB);
    merge_kernel<<<NQ, 256, 0, stream>>>(cand, out, NB);
}

// Round 2
// 512.318 us; speedup vs baseline: 1.7920x; 1.7920x over previous
//
#include <hip/hip_runtime.h>
#include <hip/hip_bf16.h>

#define D 768
#define NQ 64
#define NT 128          // corpus rows per block
#define KC 64           // k-chunk (fp32 cols per LDS tile)
#define NCH (D / KC)    // 12
#define TPB 256
#define SIMSTRIDE 133
#define NS 8            // merge1 segments per query

typedef float    f32x4 __attribute__((ext_vector_type(4)));
typedef _Float16 h16x8 __attribute__((ext_vector_type(8)));

typedef const void __attribute__((address_space(1)))* gas_ptr;
typedef void __attribute__((address_space(3)))* las_ptr;

// ---------- top-k helpers (static-indexed: stays in VGPRs) ----------
__device__ __forceinline__ bool kbetter(float v1, int i1, float v2, int i2) {
    return (v1 > v2) || (v1 == v2 && i1 < i2);
}

__device__ __forceinline__ void topk_insert(float (&tv)[16], int (&ti)[16], float v, int idx) {
    if (!kbetter(v, idx, tv[15], ti[15])) return;
    tv[15] = v; ti[15] = idx;
    #pragma unroll
    for (int s = 15; s >= 1; --s) {
        bool sw = kbetter(tv[s], ti[s], tv[s-1], ti[s-1]);
        float av = sw ? tv[s] : tv[s-1];
        float bv = sw ? tv[s-1] : tv[s];
        int   ai = sw ? ti[s] : ti[s-1];
        int   bi = sw ? ti[s-1] : ti[s];
        tv[s-1] = av; tv[s] = bv; ti[s-1] = ai; ti[s] = bi;
    }
}

__device__ __forceinline__ void bitonic16(float (&v)[16], int (&ix)[16]) {
    #pragma unroll
    for (int d = 8; d >= 1; d >>= 1) {
        #pragma unroll
        for (int i = 0; i < 16; ++i) {
            if ((i & d) == 0) {
                int j = i | d;
                bool sw = kbetter(v[j], ix[j], v[i], ix[i]);
                float av = sw ? v[j] : v[i];
                float bv = sw ? v[i] : v[j];
                int   ai = sw ? ix[j] : ix[i];
                int   bi = sw ? ix[i] : ix[j];
                v[i] = av; v[j] = bv; ix[i] = ai; ix[j] = bi;
            }
        }
    }
}

__device__ __forceinline__ void lane_merge(float (&v)[16], int (&ix)[16], int mask) {
    float pv[16]; int pix[16];
    #pragma unroll
    for (int i = 0; i < 16; ++i) {
        pv[i]  = __shfl_xor(v[15 - i], mask);
        pix[i] = __shfl_xor(ix[15 - i], mask);
    }
    #pragma unroll
    for (int i = 0; i < 16; ++i) {
        if (kbetter(pv[i], pix[i], v[i], ix[i])) { v[i] = pv[i]; ix[i] = pix[i]; }
    }
    bitonic16(v, ix);
}

// full bitonic sort of one value/index per lane across a 64-lane wave, descending
__device__ __forceinline__ void sort64(float& v, int& ix, int l) {
    #pragma unroll
    for (int k = 2; k <= 64; k <<= 1) {
        #pragma unroll
        for (int j = k >> 1; j >= 1; j >>= 1) {
            float ov = __shfl_xor(v, j);
            int   oi = __shfl_xor(ix, j);
            bool dirDesc = ((l & k) == 0);
            bool lower   = ((l & j) == 0);
            bool takeBetter = (lower == dirDesc);
            bool ob = kbetter(ov, oi, v, ix);
            if (takeBetter == ob) { v = ov; ix = oi; }
        }
    }
}

// ---------- kernel 0: normalize Q rows, store fp16 hi/lo split in MFMA-fragment order ----------
// layout: qf*[c][kk][qf][lane][8 halves]; lane = (qrow&15) + ((col>>3)&3)*16
__global__ __launch_bounds__(256)
void prep_kernel(const float* __restrict__ query, _Float16* __restrict__ qfh,
                 _Float16* __restrict__ qfl) {
    int b = blockIdx.x, t = threadIdx.x;
    const float* row = query + b * D;
    float vals[3]; float s = 0.f;
    #pragma unroll
    for (int j = 0; j < 3; ++j) { vals[j] = row[t + 256 * j]; s += vals[j] * vals[j]; }
    #pragma unroll
    for (int m = 1; m < 64; m <<= 1) s += __shfl_xor(s, m);
    __shared__ float ws4[4];
    if ((t & 63) == 0) ws4[t >> 6] = s;
    __syncthreads();
    float qn = sqrtf(ws4[0] + ws4[1] + ws4[2] + ws4[3]);
    int qf = b >> 4;
    #pragma unroll
    for (int j = 0; j < 3; ++j) {
        int col = t + 256 * j;
        float vn = vals[j] / qn;
        _Float16 h = (_Float16)vn;
        float r = vn - (float)h;
        _Float16 l2 = (_Float16)(r * 2048.0f);
        int cc = col >> 6, kk = (col >> 5) & 1, unit = (col >> 3) & 3, sub = col & 7;
        int lane = (b & 15) + unit * 16;
        size_t off = ((((size_t)cc * 2 + kk) * 4 + qf) * 64 + lane) * 8 + sub;
        qfh[off] = h;
        qfl[off] = l2;
    }
}

// ---------- kernel 1: async-staged fp32 tiles, split-fp16 MFMA, per-block top-16 ----------
__global__ __launch_bounds__(TPB, 2)
void sim_topk_kernel(const float* __restrict__ corpus,
                     const _Float16* __restrict__ qfh,
                     const _Float16* __restrict__ qfl,
                     float2* __restrict__ cand,   // [NQ][NB][16]
                     int N, int NB) {
    // two fp32 tiles [128 rows][64 cols], 32KB each; sim overlays them at the end
    __shared__ __align__(16) float lds[2 * NT * KC];
    int t = threadIdx.x, w = t >> 6, l = t & 63;
    int b = blockIdx.x;
    long n0 = (long)b * NT;

    f32x4 accH[4][2], accX[4][2];
    #pragma unroll
    for (int qf = 0; qf < 4; ++qf)
        #pragma unroll
        for (int nfl = 0; nfl < 2; ++nfl) { accH[qf][nfl] = (f32x4)(0.f); accX[qf][nfl] = (f32x4)(0.f); }
    float psum[2] = {0.f, 0.f};

    // async stage chunk c into buffer buf: linear LDS dest, inverse-XOR-swizzled global src
    auto STAGE = [&](int c, int buf) {
        #pragma unroll
        for (int j = 0; j < 8; ++j) {
            int U = t + TPB * j;              // lane0 of each wave holds the wave-uniform base
            int row = U >> 4, unit = U & 15;
            long grow = n0 + row; if (grow >= N) grow = N - 1;
            int su = unit ^ (row & 15);
            const float* src = corpus + (size_t)grow * D + c * KC + su * 4;
            float* dst = &lds[buf * (NT * KC) + (size_t)U * 4];
            __builtin_amdgcn_global_load_lds((gas_ptr)(const void*)src, (las_ptr)(void*)dst, 16, 0, 0);
        }
    };

    STAGE(0, 0);
    __syncthreads();   // drains vmcnt(0): tile 0 resident

    for (int c = 0; c < NCH; ++c) {
        int buf = c & 1;
        if (c + 1 < NCH) STAGE(c + 1, buf ^ 1);   // prefetch next tile (in flight during compute)

        const float* bufp = &lds[buf * (NT * KC)];
        #pragma unroll
        for (int kk = 0; kk < 2; ++kk) {
            // coalesced Q fragments (packed by prep): 1KB contiguous per instruction
            h16x8 qh[4], ql[4];
            #pragma unroll
            for (int qf = 0; qf < 4; ++qf) {
                size_t qoff = ((((size_t)c * 2 + kk) * 4 + qf) * 64 + l) * 8;
                qh[qf] = *(const h16x8*)(qfh + qoff);
                ql[qf] = *(const h16x8*)(qfl + qoff);
            }
            #pragma unroll
            for (int nfl = 0; nfl < 2; ++nfl) {
                int row = w * 32 + nfl * 16 + (l & 15);
                int u0 = kk * 8 + ((l >> 4) << 1);
                f32x4 x0 = *(const f32x4*)(bufp + row * KC + ((u0 ^ (row & 15)) << 2));
                f32x4 x1 = *(const f32x4*)(bufp + row * KC + (((u0 + 1) ^ (row & 15)) << 2));
                h16x8 hi, lo;
                float ps = 0.f;
                #pragma unroll
                for (int i2 = 0; i2 < 4; ++i2) {
                    float v0 = x0[i2]; _Float16 h0 = (_Float16)v0;
                    hi[i2] = h0; lo[i2] = (_Float16)((v0 - (float)h0) * 2048.0f);
                    ps += v0 * v0;
                    float v1 = x1[i2]; _Float16 h1 = (_Float16)v1;
                    hi[4 + i2] = h1; lo[4 + i2] = (_Float16)((v1 - (float)h1) * 2048.0f);
                    ps += v1 * v1;
                }
                psum[nfl] += ps;
                #pragma unroll
                for (int qf = 0; qf < 4; ++qf) {
                    accH[qf][nfl] = __builtin_amdgcn_mfma_f32_16x16x32_f16(qh[qf], hi, accH[qf][nfl], 0, 0, 0);
                    accX[qf][nfl] = __builtin_amdgcn_mfma_f32_16x16x32_f16(qh[qf], lo, accX[qf][nfl], 0, 0, 0);
                    accX[qf][nfl] = __builtin_amdgcn_mfma_f32_16x16x32_f16(ql[qf], hi, accX[qf][nfl], 0, 0, 0);
                }
            }
        }
        __syncthreads();   // drains vmcnt(0) (next tile landed) + releases this buffer
    }

    // corpus norms: this lane's psum covers its col-slice; lanes l, l^16, l^32, l^48 share a row
    float cnv[2];
    #pragma unroll
    for (int nfl = 0; nfl < 2; ++nfl) {
        float s = psum[nfl];
        s += __shfl_xor(s, 16);
        s += __shfl_xor(s, 32);
        cnv[nfl] = sqrtf(s);
    }

    // sim overlay (all tile reads are done; final loop iteration ended with a barrier)
    float* sim = (float*)lds;
    #pragma unroll
    for (int nfl = 0; nfl < 2; ++nfl) {
        int n = w * 32 + nfl * 16 + (l & 15);
        #pragma unroll
        for (int qf = 0; qf < 4; ++qf) {
            #pragma unroll
            for (int r = 0; r < 4; ++r) {
                int q = qf * 16 + ((l >> 4) << 2) + r;
                float dot = accH[qf][nfl][r] + accX[qf][nfl][r] * (1.0f / 2048.0f);
                sim[q * SIMSTRIDE + n] = dot / cnv[nfl];
            }
        }
    }
    __syncthreads();

    // per-query top-16 over the block's 128 rows: 4 threads per query
    int q = t >> 2, cc = t & 3;
    float tv[16]; int ti[16];
    #pragma unroll
    for (int s = 0; s < 16; ++s) { tv[s] = -INFINITY; ti[s] = 0x7fffffff; }
    for (int i = 0; i < 32; ++i) {
        int n = cc * 32 + i;
        long g = n0 + n;
        if (g < N) topk_insert(tv, ti, sim[q * SIMSTRIDE + n], (int)g);
    }
    lane_merge(tv, ti, 1);
    lane_merge(tv, ti, 2);
    if ((l & 3) == 0) {
        float2* dst = cand + ((size_t)q * NB + b) * 16;
        #pragma unroll
        for (int s = 0; s < 16; ++s) dst[s] = make_float2(tv[s], __int_as_float(ti[s]));
    }
}

// ---------- kernel 2a: partial merge — 8 segments per query ----------
__global__ __launch_bounds__(256)
void merge1_kernel(const float2* __restrict__ cand, float2* __restrict__ cand2, int NB) {
    int q = blockIdx.x >> 3, seg = blockIdx.x & (NS - 1);
    int t = threadIdx.x, w = t >> 6, l = t & 63;
    int total = NB * 16;
    int chunk = (total + NS - 1) / NS;
    int e0 = seg * chunk, e1 = min(total, e0 + chunk);
    const float2* src = cand + (size_t)q * total;
    float tv[16]; int ti[16];
    #pragma unroll
    for (int s = 0; s < 16; ++s) { tv[s] = -INFINITY; ti[s] = 0x7fffffff; }
    for (int e = e0 + t; e < e1; e += 256) {
        float2 ce = src[e];
        topk_insert(tv, ti, ce.x, __float_as_int(ce.y));
    }
    lane_merge(tv, ti, 1);  lane_merge(tv, ti, 2);  lane_merge(tv, ti, 4);
    lane_merge(tv, ti, 8);  lane_merge(tv, ti, 16); lane_merge(tv, ti, 32);
    __shared__ float2 stage[64];
    if (l == 0) {
        #pragma unroll
        for (int s = 0; s < 16; ++s) stage[w * 16 + s] = make_float2(tv[s], __int_as_float(ti[s]));
    }
    __syncthreads();
    if (t < 64) {
        float2 ce = stage[t];
        float v = ce.x; int ix = __float_as_int(ce.y);
        sort64(v, ix, t);
        if (t < 16) cand2[((size_t)q * NS + seg) * 16 + t] = make_float2(v, __int_as_float(ix));
    }
}

// ---------- kernel 2b: final merge of 8x16=128 candidates per query ----------
__global__ __launch_bounds__(64)
void merge2_kernel(const float2* __restrict__ cand2, float* __restrict__ out) {
    int q = blockIdx.x, l = threadIdx.x;
    const float2* src = cand2 + (size_t)q * (NS * 16);
    float2 a = src[l], b = src[l + 64];
    float v1 = a.x; int i1 = __float_as_int(a.y);
    float v2 = b.x; int i2 = __float_as_int(b.y);
    sort64(v1, i1, l);
    sort64(v2, i2, l);
    // top-16 of union lives in A[0..15] ∪ B[0..15]
    float sv = __shfl(v2, (l - 16) & 63);
    int   si = __shfl(i2, (l - 16) & 63);
    float mv = (l < 16) ? v1 : ((l < 32) ? sv : -INFINITY);
    int   mi = (l < 16) ? i1 : ((l < 32) ? si : 0x7fffffff);
    sort64(mv, mi, l);
    if (l < 16) {
        out[q * 16 + l]           = mv;           // values
        out[NQ * 16 + q * 16 + l] = (float)mi;    // indices as fp32
    }
}

extern "C" void kernel_launch(void* const* d_in, const int* in_sizes, int n_in,
                              void* d_out, int out_size, void* d_ws, size_t ws_size,
                              hipStream_t stream) {
    const float* query  = (const float*)d_in[0];
    const float* corpus = (const float*)d_in[1];
    int N  = in_sizes[1] / D;            // 500000
    int NB = (N + NT - 1) / NT;          // 3907
    char* ws = (char*)d_ws;
    _Float16* qfh = (_Float16*)ws;                               // 98304 B
    _Float16* qfl = (_Float16*)(ws + 98304);                     // 98304 B
    float2*  cand = (float2*)(ws + 196608);                      // 64*NB*16*8 B
    size_t candBytes = (size_t)NQ * NB * 16 * sizeof(float2);
    float2* cand2 = (float2*)(ws + 196608 + candBytes);          // 64*8*16*8 = 64KB
    float*   out  = (float*)d_out;

    prep_kernel<<<NQ, 256, 0, stream>>>(query, qfh, qfl);
    sim_topk_kernel<<<NB, TPB, 0, stream>>>(corpus, qfh, qfl, cand, N, NB);
    merge1_kernel<<<NQ * NS, 256, 0, stream>>>(cand, cand2, NB);
    merge2_kernel<<<NQ, 64, 0, stream>>>(cand2, out);
}